// Round 1
// baseline (21630.602 us; speedup 1.0000x reference)
//
#include <hip/hip_runtime.h>

// Problem constants
#define B_ 64
#define T_ 1024
#define D_ 512   // IN_DIM
#define U_ 512   // UNITS
#define O_ 128   // ORDER

typedef __attribute__((ext_vector_type(8))) short short8;
typedef __attribute__((ext_vector_type(4))) float floatx4;

__device__ __forceinline__ unsigned short f2bf(float f){
  unsigned u = __float_as_uint(f);
  u += 0x7FFFu + ((u >> 16) & 1u);          // RNE
  return (unsigned short)(u >> 16);
}
__device__ __forceinline__ float bf2f(unsigned short h){
  return __uint_as_float(((unsigned)h) << 16);
}

// ---------------------------------------------------------------------------
// Transpose+split-convert input_kernel:  wxt_hi/lo[n][k] = bf16split(Wx[k][n])
// ---------------------------------------------------------------------------
__global__ void k_wxt(const float* __restrict__ wx,
                      unsigned short* __restrict__ whi,
                      unsigned short* __restrict__ wlo){
  int i = blockIdx.x * blockDim.x + threadIdx.x;
  int stride = gridDim.x * blockDim.x;
  for(; i < D_ * U_; i += stride){
    int n = i >> 9, k = i & 511;
    float v = wx[k * U_ + n];
    unsigned short h = f2bf(v);
    whi[i] = h;
    wlo[i] = f2bf(v - bf2f(h));
  }
}

// ---------------------------------------------------------------------------
// ux[row] = x[row,:] . input_encoders   (row = b*T + t)
// ---------------------------------------------------------------------------
__global__ void k_ux(const float* __restrict__ x, const float* __restrict__ ie,
                     float* __restrict__ ux){
  int w = threadIdx.x >> 6, lane = threadIdx.x & 63;
  int wid = blockIdx.x * 4 + w;            // 0..4095
  for(int it = 0; it < 16; ++it){
    int row = wid * 16 + it;               // 0..65535
    const float* xr = x + (size_t)row * D_;
    float p = 0.f;
#pragma unroll
    for(int i = 0; i < 2; ++i){
      float4 xv = *(const float4*)(xr + lane * 8 + i * 4);
      float4 ev = *(const float4*)(ie + lane * 8 + i * 4);
      p += xv.x * ev.x + xv.y * ev.y + xv.z * ev.z + xv.w * ev.w;
    }
#pragma unroll
    for(int off = 32; off; off >>= 1) p += __shfl_down(p, off, 64);
    if(lane == 0) ux[row] = p;
  }
}

// ---------------------------------------------------------------------------
// P = x @ Wx   (M=65536, K=512, N=512), fp32-accurate via bf16 hi/lo split.
// 128x128 block tile, 4 waves, each wave a 64x64 quadrant of 16x16 MFMA tiles.
// ---------------------------------------------------------------------------
__global__ __launch_bounds__(256) void k_gemm(const float* __restrict__ x,
                                              const unsigned short* __restrict__ bhi,
                                              const unsigned short* __restrict__ blo,
                                              float* __restrict__ P){
  __shared__ __align__(16) unsigned short AsH[128 * 40]; // pad row to 40 ushorts
  __shared__ __align__(16) unsigned short AsL[128 * 40];
  __shared__ __align__(16) unsigned short BsH[128 * 40];
  __shared__ __align__(16) unsigned short BsL[128 * 40];
  int tid = threadIdx.x;
  int w = tid >> 6, lane = tid & 63, quad = lane >> 4, l15 = lane & 15;
  int m0 = (blockIdx.x >> 2) * 128, n0 = (blockIdx.x & 3) * 128;
  int wrow = (w >> 1) * 64, wcol = (w & 1) * 64;

  floatx4 z4 = {0.f, 0.f, 0.f, 0.f};
  floatx4 acc[4][4];
#pragma unroll
  for(int i = 0; i < 4; ++i)
#pragma unroll
    for(int j = 0; j < 4; ++j) acc[i][j] = z4;

  int r = tid >> 1, half = tid & 1;
  for(int kc = 0; kc < D_; kc += 32){
    { // stage A (convert fp32 -> bf16 hi/lo) and B (pre-converted)
      const float* ga = x + (size_t)(m0 + r) * D_ + kc + half * 16;
      float4 f0 = *(const float4*)(ga + 0);
      float4 f1 = *(const float4*)(ga + 4);
      float4 f2 = *(const float4*)(ga + 8);
      float4 f3 = *(const float4*)(ga + 12);
      float fv[16] = {f0.x, f0.y, f0.z, f0.w, f1.x, f1.y, f1.z, f1.w,
                      f2.x, f2.y, f2.z, f2.w, f3.x, f3.y, f3.z, f3.w};
      unsigned ph[8], pl[8];
#pragma unroll
      for(int c = 0; c < 8; ++c){
        float a0 = fv[2 * c], a1 = fv[2 * c + 1];
        unsigned short h0 = f2bf(a0), h1 = f2bf(a1);
        unsigned short q0 = f2bf(a0 - bf2f(h0)), q1 = f2bf(a1 - bf2f(h1));
        ph[c] = (unsigned)h0 | ((unsigned)h1 << 16);
        pl[c] = (unsigned)q0 | ((unsigned)q1 << 16);
      }
      int o = r * 40 + half * 16;
      *(uint4*)&AsH[o]     = make_uint4(ph[0], ph[1], ph[2], ph[3]);
      *(uint4*)&AsH[o + 8] = make_uint4(ph[4], ph[5], ph[6], ph[7]);
      *(uint4*)&AsL[o]     = make_uint4(pl[0], pl[1], pl[2], pl[3]);
      *(uint4*)&AsL[o + 8] = make_uint4(pl[4], pl[5], pl[6], pl[7]);
      const unsigned short* gh = bhi + (size_t)(n0 + r) * D_ + kc + half * 16;
      const unsigned short* gl = blo + (size_t)(n0 + r) * D_ + kc + half * 16;
      *(uint4*)&BsH[o]     = *(const uint4*)(gh);
      *(uint4*)&BsH[o + 8] = *(const uint4*)(gh + 8);
      *(uint4*)&BsL[o]     = *(const uint4*)(gl);
      *(uint4*)&BsL[o + 8] = *(const uint4*)(gl + 8);
    }
    __syncthreads();
    short8 ah[4], al[4], bh[4], bl[4];
#pragma unroll
    for(int mi = 0; mi < 4; ++mi){
      int o = (wrow + mi * 16 + l15) * 40 + quad * 8;
      ah[mi] = *(const short8*)&AsH[o];
      al[mi] = *(const short8*)&AsL[o];
    }
#pragma unroll
    for(int ni = 0; ni < 4; ++ni){
      int o = (wcol + ni * 16 + l15) * 40 + quad * 8;
      bh[ni] = *(const short8*)&BsH[o];
      bl[ni] = *(const short8*)&BsL[o];
    }
#pragma unroll
    for(int mi = 0; mi < 4; ++mi)
#pragma unroll
      for(int ni = 0; ni < 4; ++ni){
        floatx4 a = acc[mi][ni];
        a = __builtin_amdgcn_mfma_f32_16x16x32_bf16(ah[mi], bh[ni], a, 0, 0, 0);
        a = __builtin_amdgcn_mfma_f32_16x16x32_bf16(al[mi], bh[ni], a, 0, 0, 0);
        a = __builtin_amdgcn_mfma_f32_16x16x32_bf16(ah[mi], bl[ni], a, 0, 0, 0);
        acc[mi][ni] = a;
      }
    __syncthreads();
  }
#pragma unroll
  for(int mi = 0; mi < 4; ++mi)
#pragma unroll
    for(int ni = 0; ni < 4; ++ni){
      int col = n0 + wcol + ni * 16 + l15;
#pragma unroll
      for(int rr = 0; rr < 4; ++rr){
        int row = m0 + wrow + mi * 16 + quad * 4 + rr;
        P[(size_t)row * U_ + col] = acc[mi][ni][rr];
      }
    }
}

// ---------------------------------------------------------------------------
// Sequential scan. 256 WGs = 64 batches x 4 column-slices (128 cols each).
// Wh slice lives in persistent VGPRs as MFMA B-frags (bf16 hi+lo).
// AT, Wm slice in LDS fp32 (transposed, stride 132 to kill bank conflicts).
// Per-step slice exchange via agent-scope atomics + step-counter flags.
// LDS ~140KB -> exactly 1 WG/CU -> all 256 WGs co-resident.
// ---------------------------------------------------------------------------
__global__ __launch_bounds__(256, 1) void k_scan(
    const float* __restrict__ he, const float* __restrict__ me,
    const float* __restrict__ Wh, const float* __restrict__ Wm,
    const float* __restrict__ AT, const float* __restrict__ BTv,
    const float* __restrict__ Pm, const float* __restrict__ ux,
    float* __restrict__ out,
    float* __restrict__ hbuf, int* __restrict__ flags)
{
  __shared__ float AT_l[O_ * 132];          // transposed [j][k], 67584 B
  __shared__ float Wm_l[O_ * 132];          // transposed [j][k], 67584 B
  __shared__ float h_l[U_];
  __shared__ __align__(16) unsigned short h_hi[U_];
  __shared__ __align__(16) unsigned short h_lo[U_];
  __shared__ __align__(16) float m_l[O_];
  __shared__ float he_l[U_];
  __shared__ float me_l[O_];
  __shared__ float bt_l[O_];
  __shared__ float scr[8];
  __shared__ float scr_acc[128];
  __shared__ float u_sh;

  int tid = threadIdx.x;
  int w = tid >> 6, lane = tid & 63, quad = lane >> 4, l15 = lane & 15;
  int b = blockIdx.x & 63, g = blockIdx.x >> 6;   // same-batch WGs share XCD (bid%8==b%8)

  // ---- one-time init ----
  for(int i = tid; i < O_ * O_; i += 256){
    int k = i >> 7, j = i & 127;
    AT_l[j * 132 + k] = AT[i];
    Wm_l[j * 132 + k] = Wm[k * U_ + g * 128 + j];
  }
  for(int i = tid; i < U_; i += 256) he_l[i] = he[i];
  if(tid < O_){ me_l[tid] = me[tid]; bt_l[tid] = BTv[tid]; m_l[tid] = 0.f; }
  h_l[tid] = 0.f; h_l[tid + 256] = 0.f;

  // Wh slice -> persistent B-frags (bf16 hi/lo): B[k][n], lane holds
  // k = kf*32 + quad*8 + i, n = g*128 + w*32 + nt*16 + l15
  short8 whf_h[32], whf_l[32];
#pragma unroll
  for(int kf = 0; kf < 16; ++kf){
#pragma unroll
    for(int nt = 0; nt < 2; ++nt){
      int ncol = g * 128 + w * 32 + nt * 16 + l15;
      short8 vh, vl;
#pragma unroll
      for(int i = 0; i < 8; ++i){
        int k = kf * 32 + quad * 8 + i;
        float v = Wh[(size_t)k * U_ + ncol];
        unsigned short hh = f2bf(v);
        vh[i] = (short)hh;
        vl[i] = (short)f2bf(v - bf2f(hh));
      }
      whf_h[kf * 2 + nt] = vh;
      whf_l[kf * 2 + nt] = vl;
    }
  }
  __syncthreads();

  const int sib1 = (g + 1) & 3, sib2 = (g + 2) & 3, sib3 = (g + 3) & 3;
  floatx4 z4 = {0.f, 0.f, 0.f, 0.f};

  for(int t = 0; t < T_; ++t){
    // A) prefetch P for this step
    float pval = 0.f;
    if(tid < 128) pval = Pm[((size_t)b * T_ + t) * U_ + g * 128 + tid];

    // B) m @ AT partial (uses OLD m; independent of gather)
    float y_at = 0.f;
    if(tid < 128){
      const float* atr = &AT_l[tid * 132];
#pragma unroll
      for(int kb = 0; kb < 32; ++kb){
        float4 a4 = *(const float4*)(atr + kb * 4);
        float4 m4 = *(const float4*)(&m_l[kb * 4]);
        y_at += a4.x * m4.x + a4.y * m4.y + a4.z * m4.z + a4.w * m4.w;
      }
    }

    // C/D/E) gather siblings' h_{t-1} slices
    if(t > 0){
      if(tid < 3){
        int sg = (tid == 0) ? sib1 : ((tid == 1) ? sib2 : sib3);
        int cnt = 0;
        while(__hip_atomic_load(&flags[b * 4 + sg], __ATOMIC_ACQUIRE,
                                __HIP_MEMORY_SCOPE_AGENT) < t){
          __builtin_amdgcn_s_sleep(1);
          if(++cnt > (1 << 22)) break;   // failsafe: no hang on bug
        }
      }
      __syncthreads();
      if(tid < 128){
        int par = (t - 1) & 1;
        float v1 = __hip_atomic_load(&hbuf[((b * 2 + par) * 4 + sib1) * 128 + tid],
                                     __ATOMIC_RELAXED, __HIP_MEMORY_SCOPE_AGENT);
        float v2 = __hip_atomic_load(&hbuf[((b * 2 + par) * 4 + sib2) * 128 + tid],
                                     __ATOMIC_RELAXED, __HIP_MEMORY_SCOPE_AGENT);
        float v3 = __hip_atomic_load(&hbuf[((b * 2 + par) * 4 + sib3) * 128 + tid],
                                     __ATOMIC_RELAXED, __HIP_MEMORY_SCOPE_AGENT);
        h_l[sib1 * 128 + tid] = v1;
        h_l[sib2 * 128 + tid] = v2;
        h_l[sib3 * 128 + tid] = v3;
      }
    }
    __syncthreads();  // F: h_l complete

    // G) split-convert h to bf16 hi/lo + u partial sums
    {
      float hv0 = h_l[tid], hv1 = h_l[tid + 256];
      unsigned short h0 = f2bf(hv0), h1 = f2bf(hv1);
      h_hi[tid] = h0;              h_hi[tid + 256] = h1;
      h_lo[tid] = f2bf(hv0 - bf2f(h0));
      h_lo[tid + 256] = f2bf(hv1 - bf2f(h1));
      float p = hv0 * he_l[tid] + hv1 * he_l[tid + 256];
      if(tid < O_) p += m_l[tid] * me_l[tid];   // old m
#pragma unroll
      for(int off = 32; off; off >>= 1) p += __shfl_down(p, off, 64);
      if(lane == 0) scr[w] = p;
    }
    __syncthreads();  // H
    if(tid == 0) u_sh = ux[b * T_ + t] + scr[0] + scr[1] + scr[2] + scr[3];
    __syncthreads();  // J

    // K) h_{t-1} @ Wh slice via MFMA, fp32-accurate (hi*hi + lo*hi + hi*lo)
    floatx4 a00 = z4, a01 = z4, a02 = z4, a10 = z4, a11 = z4, a12 = z4;
#pragma unroll
    for(int kf = 0; kf < 16; ++kf){
      short8 ah = *(const short8*)&h_hi[kf * 32 + quad * 8];
      short8 al = *(const short8*)&h_lo[kf * 32 + quad * 8];
      a00 = __builtin_amdgcn_mfma_f32_16x16x32_bf16(ah, whf_h[kf * 2 + 0], a00, 0, 0, 0);
      a01 = __builtin_amdgcn_mfma_f32_16x16x32_bf16(al, whf_h[kf * 2 + 0], a01, 0, 0, 0);
      a02 = __builtin_amdgcn_mfma_f32_16x16x32_bf16(ah, whf_l[kf * 2 + 0], a02, 0, 0, 0);
      a10 = __builtin_amdgcn_mfma_f32_16x16x32_bf16(ah, whf_h[kf * 2 + 1], a10, 0, 0, 0);
      a11 = __builtin_amdgcn_mfma_f32_16x16x32_bf16(al, whf_h[kf * 2 + 1], a11, 0, 0, 0);
      a12 = __builtin_amdgcn_mfma_f32_16x16x32_bf16(ah, whf_l[kf * 2 + 1], a12, 0, 0, 0);
    }

    // L) finish m update: m_t = m + m@AT + u*BT
    float u_val = u_sh;
    if(tid < O_){
      float mn = m_l[tid] + y_at + u_val * bt_l[tid];
      m_l[tid] = mn;          // safe: all reads of old m happened before F
    }
    __syncthreads();  // M: new m visible

    // N) m_t @ Wm slice (fp32 VALU) + extract MFMA row 0
    float y_wm = 0.f;
    if(tid < 128){
      const float* wmr = &Wm_l[tid * 132];
#pragma unroll
      for(int kb = 0; kb < 32; ++kb){
        float4 a4 = *(const float4*)(wmr + kb * 4);
        float4 m4 = *(const float4*)(&m_l[kb * 4]);
        y_wm += a4.x * m4.x + a4.y * m4.y + a4.z * m4.z + a4.w * m4.w;
      }
    }
    if(quad == 0){   // C/D row 0 lives in lanes 0-15, reg 0
      scr_acc[w * 32 + l15]      = a00[0] + a01[0] + a02[0];
      scr_acc[w * 32 + 16 + l15] = a10[0] + a11[0] + a12[0];
    }
    __syncthreads();  // O

    // P) combine, tanh, store, publish
    if(tid < 128){
      float pre = pval + scr_acc[tid] + y_wm;
      float hv = tanhf(pre);
      out[((size_t)b * T_ + t) * U_ + g * 128 + tid] = hv;
      h_l[g * 128 + tid] = hv;                 // own slice for next step
      int par = t & 1;
      __hip_atomic_store(&hbuf[((b * 2 + par) * 4 + g) * 128 + tid], hv,
                         __ATOMIC_RELAXED, __HIP_MEMORY_SCOPE_AGENT);
    }
    __threadfence();
    __syncthreads();  // Q
    if(tid == 0)
      __hip_atomic_store(&flags[b * 4 + g], t + 1, __ATOMIC_RELEASE,
                         __HIP_MEMORY_SCOPE_AGENT);
  }
}

// ---------------------------------------------------------------------------
extern "C" void kernel_launch(void* const* d_in, const int* in_sizes, int n_in,
                              void* d_out, int out_size, void* d_ws, size_t ws_size,
                              hipStream_t stream){
  const float* x  = (const float*)d_in[0];   // (64,1024,512)
  const float* ie = (const float*)d_in[1];   // (512,1)
  const float* he = (const float*)d_in[2];   // (512,1)
  const float* me = (const float*)d_in[3];   // (128,1)
  const float* wx = (const float*)d_in[4];   // (512,512)
  const float* wh = (const float*)d_in[5];   // (512,512)
  const float* wm = (const float*)d_in[6];   // (128,512)
  const float* at = (const float*)d_in[7];   // (128,128)
  const float* bt = (const float*)d_in[8];   // (1,128)
  float* out = (float*)d_out;

  // workspace layout (needs ~136 MB)
  char* ws = (char*)d_ws;
  float*          P     = (float*)(ws);                          // 134217728 B
  float*          uxp   = (float*)(ws + 134217728);              //    262144 B
  unsigned short* wxt_h = (unsigned short*)(ws + 134479872);     //    524288 B
  unsigned short* wxt_l = (unsigned short*)(ws + 135004160);     //    524288 B
  float*          hbuf  = (float*)(ws + 135528448);              //    262144 B
  int*            flags = (int*)(ws + 135790592);                //      1024 B

  k_wxt <<<256, 256, 0, stream>>>(wx, wxt_h, wxt_l);
  k_ux  <<<1024, 256, 0, stream>>>(x, ie, uxp);
  k_gemm<<<2048, 256, 0, stream>>>(x, wxt_h, wxt_l, P);
  k_scan<<<256, 256, 0, stream>>>(he, me, wh, wm, at, bt, P, uxp, out, hbuf, flags);
}

// Round 2
// 3361.991 us; speedup vs baseline: 6.4339x; 6.4339x over previous
//
#include <hip/hip_runtime.h>

// Problem constants
#define B_ 64
#define T_ 1024
#define D_ 512   // IN_DIM
#define U_ 512   // UNITS
#define O_ 128   // ORDER

typedef __attribute__((ext_vector_type(8))) short short8;
typedef __attribute__((ext_vector_type(4))) float floatx4;

__device__ __forceinline__ unsigned short f2bf(float f){
  unsigned u = __float_as_uint(f);
  u += 0x7FFFu + ((u >> 16) & 1u);          // RNE
  return (unsigned short)(u >> 16);
}
__device__ __forceinline__ float bf2f(unsigned short h){
  return __uint_as_float(((unsigned)h) << 16);
}

// ---------------------------------------------------------------------------
// Transpose+split-convert input_kernel:  wxt_hi/lo[n][k] = bf16split(Wx[k][n])
// ---------------------------------------------------------------------------
__global__ void k_wxt(const float* __restrict__ wx,
                      unsigned short* __restrict__ whi,
                      unsigned short* __restrict__ wlo){
  int i = blockIdx.x * blockDim.x + threadIdx.x;
  int stride = gridDim.x * blockDim.x;
  for(; i < D_ * U_; i += stride){
    int n = i >> 9, k = i & 511;
    float v = wx[k * U_ + n];
    unsigned short h = f2bf(v);
    whi[i] = h;
    wlo[i] = f2bf(v - bf2f(h));
  }
}

// ---------------------------------------------------------------------------
// Hidden_kernel -> MFMA B-frag-linear layout (hi/lo), so k_scan init loads
// are fully coalesced. Element Wh[k][n]: g=n>>7, w=(n>>4)&7, l15=n&15,
// kf=k>>5, q=(k>>3)&3, i=k&7, lane=q*16+l15,
// pos = (((g*16+kf)*8 + w)*64 + lane)*8 + i
// ---------------------------------------------------------------------------
__global__ void k_whf(const float* __restrict__ wh,
                      unsigned short* __restrict__ fhi,
                      unsigned short* __restrict__ flo){
  int idx = blockIdx.x * blockDim.x + threadIdx.x;
  if(idx >= D_ * U_) return;
  int k = idx >> 9, n = idx & 511;
  float v = wh[idx];
  int g = n >> 7, w = (n >> 4) & 7, l15 = n & 15;
  int kf = k >> 5, q = (k >> 3) & 3, i = k & 7;
  size_t pos = ((((size_t)g * 16 + kf) * 8 + w) * 64 + (q * 16 + l15)) * 8 + i;
  unsigned short h = f2bf(v);
  fhi[pos] = h;
  flo[pos] = f2bf(v - bf2f(h));
}

// ---------------------------------------------------------------------------
// W2[k][c] = Wm[k][c] + sum_j AT[k][j]*Wm[j][c]   (W2 = (I+AT)@Wm)
// ---------------------------------------------------------------------------
__global__ void k_w2(const float* __restrict__ at, const float* __restrict__ wm,
                     float* __restrict__ w2){
  __shared__ float arow[O_];
  int k = blockIdx.x;
  if(threadIdx.x < O_) arow[threadIdx.x] = at[k * O_ + threadIdx.x];
  __syncthreads();
  int c = threadIdx.x;
  float acc = wm[k * U_ + c];
  for(int j = 0; j < O_; ++j) acc += arow[j] * wm[j * U_ + c];
  w2[k * U_ + c] = acc;
}

// bw[c] = sum_j BT[j]*Wm[j][c]
__global__ void k_bw(const float* __restrict__ bt, const float* __restrict__ wm,
                     float* __restrict__ bw){
  int c = threadIdx.x;
  float acc = 0.f;
  for(int j = 0; j < O_; ++j) acc += bt[j] * wm[j * U_ + c];
  bw[c] = acc;
}

// ---------------------------------------------------------------------------
// ux[row] = x[row,:] . input_encoders   (row = b*T + t)
// ---------------------------------------------------------------------------
__global__ void k_ux(const float* __restrict__ x, const float* __restrict__ ie,
                     float* __restrict__ ux){
  int w = threadIdx.x >> 6, lane = threadIdx.x & 63;
  int wid = blockIdx.x * 4 + w;            // 0..4095
  for(int it = 0; it < 16; ++it){
    int row = wid * 16 + it;               // 0..65535
    const float* xr = x + (size_t)row * D_;
    float p = 0.f;
#pragma unroll
    for(int i = 0; i < 2; ++i){
      float4 xv = *(const float4*)(xr + lane * 8 + i * 4);
      float4 ev = *(const float4*)(ie + lane * 8 + i * 4);
      p += xv.x * ev.x + xv.y * ev.y + xv.z * ev.z + xv.w * ev.w;
    }
#pragma unroll
    for(int off = 32; off; off >>= 1) p += __shfl_down(p, off, 64);
    if(lane == 0) ux[row] = p;
  }
}

// ---------------------------------------------------------------------------
// P = x @ Wx   (M=65536, K=512, N=512), fp32-accurate via bf16 hi/lo split.
// ---------------------------------------------------------------------------
__global__ __launch_bounds__(256) void k_gemm(const float* __restrict__ x,
                                              const unsigned short* __restrict__ bhi,
                                              const unsigned short* __restrict__ blo,
                                              float* __restrict__ P){
  __shared__ __align__(16) unsigned short AsH[128 * 40];
  __shared__ __align__(16) unsigned short AsL[128 * 40];
  __shared__ __align__(16) unsigned short BsH[128 * 40];
  __shared__ __align__(16) unsigned short BsL[128 * 40];
  int tid = threadIdx.x;
  int w = tid >> 6, lane = tid & 63, quad = lane >> 4, l15 = lane & 15;
  int m0 = (blockIdx.x >> 2) * 128, n0 = (blockIdx.x & 3) * 128;
  int wrow = (w >> 1) * 64, wcol = (w & 1) * 64;

  floatx4 z4 = {0.f, 0.f, 0.f, 0.f};
  floatx4 acc[4][4];
#pragma unroll
  for(int i = 0; i < 4; ++i)
#pragma unroll
    for(int j = 0; j < 4; ++j) acc[i][j] = z4;

  int r = tid >> 1, half = tid & 1;
  for(int kc = 0; kc < D_; kc += 32){
    {
      const float* ga = x + (size_t)(m0 + r) * D_ + kc + half * 16;
      float4 f0 = *(const float4*)(ga + 0);
      float4 f1 = *(const float4*)(ga + 4);
      float4 f2 = *(const float4*)(ga + 8);
      float4 f3 = *(const float4*)(ga + 12);
      float fv[16] = {f0.x, f0.y, f0.z, f0.w, f1.x, f1.y, f1.z, f1.w,
                      f2.x, f2.y, f2.z, f2.w, f3.x, f3.y, f3.z, f3.w};
      unsigned ph[8], pl[8];
#pragma unroll
      for(int c = 0; c < 8; ++c){
        float a0 = fv[2 * c], a1 = fv[2 * c + 1];
        unsigned short h0 = f2bf(a0), h1 = f2bf(a1);
        unsigned short q0 = f2bf(a0 - bf2f(h0)), q1 = f2bf(a1 - bf2f(h1));
        ph[c] = (unsigned)h0 | ((unsigned)h1 << 16);
        pl[c] = (unsigned)q0 | ((unsigned)q1 << 16);
      }
      int o = r * 40 + half * 16;
      *(uint4*)&AsH[o]     = make_uint4(ph[0], ph[1], ph[2], ph[3]);
      *(uint4*)&AsH[o + 8] = make_uint4(ph[4], ph[5], ph[6], ph[7]);
      *(uint4*)&AsL[o]     = make_uint4(pl[0], pl[1], pl[2], pl[3]);
      *(uint4*)&AsL[o + 8] = make_uint4(pl[4], pl[5], pl[6], pl[7]);
      const unsigned short* gh = bhi + (size_t)(n0 + r) * D_ + kc + half * 16;
      const unsigned short* gl = blo + (size_t)(n0 + r) * D_ + kc + half * 16;
      *(uint4*)&BsH[o]     = *(const uint4*)(gh);
      *(uint4*)&BsH[o + 8] = *(const uint4*)(gh + 8);
      *(uint4*)&BsL[o]     = *(const uint4*)(gl);
      *(uint4*)&BsL[o + 8] = *(const uint4*)(gl + 8);
    }
    __syncthreads();
    short8 ah[4], al[4], bh[4], bl[4];
#pragma unroll
    for(int mi = 0; mi < 4; ++mi){
      int o = (wrow + mi * 16 + l15) * 40 + quad * 8;
      ah[mi] = *(const short8*)&AsH[o];
      al[mi] = *(const short8*)&AsL[o];
    }
#pragma unroll
    for(int ni = 0; ni < 4; ++ni){
      int o = (wcol + ni * 16 + l15) * 40 + quad * 8;
      bh[ni] = *(const short8*)&BsH[o];
      bl[ni] = *(const short8*)&BsL[o];
    }
#pragma unroll
    for(int mi = 0; mi < 4; ++mi)
#pragma unroll
      for(int ni = 0; ni < 4; ++ni){
        floatx4 a = acc[mi][ni];
        a = __builtin_amdgcn_mfma_f32_16x16x32_bf16(ah[mi], bh[ni], a, 0, 0, 0);
        a = __builtin_amdgcn_mfma_f32_16x16x32_bf16(al[mi], bh[ni], a, 0, 0, 0);
        a = __builtin_amdgcn_mfma_f32_16x16x32_bf16(ah[mi], bl[ni], a, 0, 0, 0);
        acc[mi][ni] = a;
      }
    __syncthreads();
  }
#pragma unroll
  for(int mi = 0; mi < 4; ++mi)
#pragma unroll
    for(int ni = 0; ni < 4; ++ni){
      int col = n0 + wcol + ni * 16 + l15;
#pragma unroll
      for(int rr = 0; rr < 4; ++rr){
        int row = m0 + wrow + mi * 16 + quad * 4 + rr;
        P[(size_t)row * U_ + col] = acc[mi][ni][rr];
      }
    }
}

// ---------------------------------------------------------------------------
// Sequential scan: 256 WGs = 64 batches x 4 col-slices (128 cols), 512 thr.
// Fence-free cross-WG exchange: tagged u64 relaxed agent atomics
// {tag=t, bf16 hi/lo packed}; parity double-buffer. No acquire/release/
// threadfence -> no buffer_inv / buffer_wbl2.
// Off-path (pre-gather): m@AT, m@W2 (uses old m), m.me, own-K h@Wh, P/ux
// prefetch. On-path: poll -> sibling-K h@Wh (36 MFMA) -> u/m/tanh -> publish.
// ---------------------------------------------------------------------------
#define HSLOT(b,par,g) ((((b)*2+(par))*4+(g))*136)

__global__ __launch_bounds__(512, 2) void k_scan(
    const float* __restrict__ he, const float* __restrict__ me,
    const float* __restrict__ bt, const float* __restrict__ at,
    const unsigned short* __restrict__ whf_hi, const unsigned short* __restrict__ whf_lo,
    const float* __restrict__ W2w, const float* __restrict__ bww,
    const float* __restrict__ Pm, const float* __restrict__ ux,
    float* __restrict__ out, unsigned long long* __restrict__ hb)
{
  __shared__ __align__(16) unsigned short ATf_h[16384], ATf_l[16384]; // 64 KB
  __shared__ __align__(16) unsigned short W2f_h[16384], W2f_l[16384]; // 64 KB
  __shared__ __align__(16) unsigned short h_hi[U_], h_lo[U_];
  __shared__ __align__(16) unsigned short m_hi[O_], m_lo[O_];
  __shared__ float m_l[O_];
  __shared__ float scr_wm[128], scr_at[128];
  __shared__ float scr_p[8], scr_ps[3], scr_md[2];
  __shared__ float scr_ownp, scr_ux;

  int tid = threadIdx.x;
  int w = tid >> 6, lane = tid & 63, quad = lane >> 4, l15 = lane & 15;
  int b = blockIdx.x & 63, g = blockIdx.x >> 6;   // batch's 4 WGs: bids b+64g
  int c = w * 16 + l15;                            // local epilogue col
  int gc = g * 128 + c;

  // ---- init: LDS frag tables for AT and W2 slice ----
  for(int idx = tid; idx < O_ * O_; idx += 512){
    int k = idx >> 7, j = idx & 127;
    float va = at[idx];
    float vw = W2w[k * U_ + g * 128 + j];
    int kf = k >> 5, q = (k >> 3) & 3, i = k & 7;
    int pos = ((kf * 8 + (j >> 4)) << 9) + (((q * 16) + (j & 15)) << 3) + i;
    unsigned short ah = f2bf(va);
    ATf_h[pos] = ah; ATf_l[pos] = f2bf(va - bf2f(ah));
    unsigned short wh2 = f2bf(vw);
    W2f_h[pos] = wh2; W2f_l[pos] = f2bf(vw - bf2f(wh2));
  }
  // Wh persistent register frags (coalesced from frag-linear layout)
  short8 whh[16], whl[16];
#pragma unroll
  for(int kf = 0; kf < 16; ++kf){
    size_t pos = ((((size_t)g * 16 + kf) * 8 + w) * 64 + lane) * 8;
    whh[kf] = *(const short8*)(whf_hi + pos);
    whl[kf] = *(const short8*)(whf_lo + pos);
  }
  float hev = he[gc], bwv = bww[gc];
  float btv = 0.f, mev = 0.f;
  if(tid < O_){ btv = bt[tid]; mev = me[tid];
                m_l[tid] = 0.f; m_hi[tid] = 0; m_lo[tid] = 0; }
  h_hi[tid] = 0; h_lo[tid] = 0;
  if(tid < 8) scr_p[tid] = 0.f;
  if(tid < 3) scr_ps[tid] = 0.f;
  if(tid == 0) scr_ownp = 0.f;

  floatx4 z4 = {0.f, 0.f, 0.f, 0.f};

  for(int t = 0; t < T_; ++t){
    __syncthreads();   // B1: prev-iter writes (h own, m, scr_p) -> this iter
    int par = t & 1, parp = (t - 1) & 1;

    // loop-top specials (off-path)
    if(tid == 448 && t > 0){
      float ps = scr_p[0] + scr_p[1] + scr_p[2] + scr_p[3] +
                 scr_p[4] + scr_p[5] + scr_p[6] + scr_p[7];
      scr_ownp = ps;
      unsigned long long v = ((unsigned long long)(unsigned)(t - 1) << 32) |
                             (unsigned long long)__float_as_uint(ps);
      __hip_atomic_store(&hb[HSLOT(b, parp, g) + 128], v,
                         __ATOMIC_RELAXED, __HIP_MEMORY_SCOPE_AGENT);
    }
    if(tid == 449) scr_ux = ux[b * T_ + t];
    float pval = 0.f;
    if(quad == 0) pval = Pm[((size_t)b * T_ + t) * U_ + gc];
    if(tid < O_){   // m.me partial (old m)
      float p = m_l[tid] * mev;
#pragma unroll
      for(int off = 32; off; off >>= 1) p += __shfl_down(p, off, 64);
      if(lane == 0) scr_md[w] = p;
    }

    // S1: own-K quarter of h@Wh (h_{t-1} own slice, from prev epilogue)
    floatx4 a0 = z4, a1 = z4, a2 = z4;
#pragma unroll
    for(int kf = 0; kf < 16; ++kf){
      if((kf >> 2) != g) continue;
      short8 ah = *(const short8*)&h_hi[kf * 32 + quad * 8];
      short8 al = *(const short8*)&h_lo[kf * 32 + quad * 8];
      a0 = __builtin_amdgcn_mfma_f32_16x16x32_bf16(ah, whh[kf], a0, 0, 0, 0);
      a1 = __builtin_amdgcn_mfma_f32_16x16x32_bf16(al, whh[kf], a1, 0, 0, 0);
      a2 = __builtin_amdgcn_mfma_f32_16x16x32_bf16(ah, whl[kf], a2, 0, 0, 0);
    }

    // S2: m_{t-1}@W2 (waves 0-3) and m_{t-1}@AT (waves 4-7) via MFMA
    {
      const unsigned short* Bh = (w < 4) ? W2f_h : ATf_h;
      const unsigned short* Bl = (w < 4) ? W2f_l : ATf_l;
      int wv4 = w & 3;
      floatx4 c0[2] = {z4, z4}, c1[2] = {z4, z4}, c2[2] = {z4, z4};
#pragma unroll
      for(int kf = 0; kf < 4; ++kf){
        short8 amh = *(const short8*)&m_hi[kf * 32 + quad * 8];
        short8 aml = *(const short8*)&m_lo[kf * 32 + quad * 8];
#pragma unroll
        for(int nt2 = 0; nt2 < 2; ++nt2){
          int f = kf * 8 + wv4 * 2 + nt2;
          short8 bh = *(const short8*)&Bh[(f << 9) + (lane << 3)];
          short8 bl = *(const short8*)&Bl[(f << 9) + (lane << 3)];
          c0[nt2] = __builtin_amdgcn_mfma_f32_16x16x32_bf16(amh, bh, c0[nt2], 0, 0, 0);
          c1[nt2] = __builtin_amdgcn_mfma_f32_16x16x32_bf16(aml, bh, c1[nt2], 0, 0, 0);
          c2[nt2] = __builtin_amdgcn_mfma_f32_16x16x32_bf16(amh, bl, c2[nt2], 0, 0, 0);
        }
      }
      if(quad == 0){
        float* dst = (w < 4) ? scr_wm : scr_at;
#pragma unroll
        for(int nt2 = 0; nt2 < 2; ++nt2)
          dst[wv4 * 32 + nt2 * 16 + l15] = c0[nt2][0] + c1[nt2][0] + c2[nt2][0];
      }
    }

    // S4: gather siblings' h_{t-1} (tagged, fence-free)
    if(t > 0){
      if(tid < 384){
        int s = tid >> 7, idx = tid & 127;
        int gs = (g + 1 + s) & 3;
        unsigned long long* ap = &hb[HSLOT(b, parp, gs) + idx];
        unsigned long long v; int cnt = 0;
        do {
          v = __hip_atomic_load(ap, __ATOMIC_RELAXED, __HIP_MEMORY_SCOPE_AGENT);
        } while((unsigned)(v >> 32) != (unsigned)(t - 1) && ++cnt < (1 << 22));
        unsigned pk = (unsigned)v;
        h_hi[gs * 128 + idx] = (unsigned short)pk;
        h_lo[gs * 128 + idx] = (unsigned short)(pk >> 16);
      } else if(tid < 387){
        int s = tid - 384, gs = (g + 1 + s) & 3;
        unsigned long long* ap = &hb[HSLOT(b, parp, gs) + 128];
        unsigned long long v; int cnt = 0;
        do {
          v = __hip_atomic_load(ap, __ATOMIC_RELAXED, __HIP_MEMORY_SCOPE_AGENT);
        } while((unsigned)(v >> 32) != (unsigned)(t - 1) && ++cnt < (1 << 22));
        scr_ps[s] = __uint_as_float((unsigned)v);
      }
    }
    __syncthreads();   // B2: gathered h + extractions visible

    // S6: sibling-K of h@Wh
#pragma unroll
    for(int kf = 0; kf < 16; ++kf){
      if((kf >> 2) == g) continue;
      short8 ah = *(const short8*)&h_hi[kf * 32 + quad * 8];
      short8 al = *(const short8*)&h_lo[kf * 32 + quad * 8];
      a0 = __builtin_amdgcn_mfma_f32_16x16x32_bf16(ah, whh[kf], a0, 0, 0, 0);
      a1 = __builtin_amdgcn_mfma_f32_16x16x32_bf16(al, whh[kf], a1, 0, 0, 0);
      a2 = __builtin_amdgcn_mfma_f32_16x16x32_bf16(ah, whl[kf], a2, 0, 0, 0);
    }

    // u = x.ie + h.he + m.me
    float u = scr_ux + scr_md[0] + scr_md[1];
    if(t > 0) u += scr_ownp + scr_ps[0] + scr_ps[1] + scr_ps[2];

    // S7: m_t = m + m@AT + u*BT (I-term fp32-exact)
    if(tid < O_){
      float mn = m_l[tid] + scr_at[tid] + u * btv;
      m_l[tid] = mn;
      unsigned short mh = f2bf(mn);
      m_hi[tid] = mh; m_lo[tid] = f2bf(mn - bf2f(mh));
    }

    // epilogue: pre-activation, tanh, publish
    if(quad == 0){
      float pre = pval + (a0[0] + a1[0] + a2[0]) + scr_wm[c] + u * bwv;
      float e = __expf(2.f * pre);
      float hv = 1.f - 2.f / (e + 1.f);
      out[((size_t)b * T_ + t) * U_ + gc] = hv;
      unsigned short hh = f2bf(hv), hl = f2bf(hv - bf2f(hh));
      h_hi[gc] = hh; h_lo[gc] = hl;
      unsigned long long v = ((unsigned long long)(unsigned)t << 32) |
                             (unsigned long long)(((unsigned)hl << 16) | (unsigned)hh);
      __hip_atomic_store(&hb[HSLOT(b, par, g) + c], v,
                         __ATOMIC_RELAXED, __HIP_MEMORY_SCOPE_AGENT);
      float p = hv * hev;
      p += __shfl_down(p, 8, 64); p += __shfl_down(p, 4, 64);
      p += __shfl_down(p, 2, 64); p += __shfl_down(p, 1, 64);
      if(l15 == 0) scr_p[w] = p;
    }
  }
}

// ---------------------------------------------------------------------------
extern "C" void kernel_launch(void* const* d_in, const int* in_sizes, int n_in,
                              void* d_out, int out_size, void* d_ws, size_t ws_size,
                              hipStream_t stream){
  const float* x  = (const float*)d_in[0];   // (64,1024,512)
  const float* ie = (const float*)d_in[1];   // (512,1)
  const float* he = (const float*)d_in[2];   // (512,1)
  const float* me = (const float*)d_in[3];   // (128,1)
  const float* wx = (const float*)d_in[4];   // (512,512)
  const float* wh = (const float*)d_in[5];   // (512,512)
  const float* wm = (const float*)d_in[6];   // (128,512)
  const float* at = (const float*)d_in[7];   // (128,128)
  const float* bt = (const float*)d_in[8];   // (1,128)
  float* out = (float*)d_out;

  // workspace layout (~137.4 MB)
  char* ws = (char*)d_ws;
  float*              P     = (float*)(ws);                          // 134217728
  float*              uxp   = (float*)(ws + 134217728);              //    262144
  unsigned short*     wxt_h = (unsigned short*)(ws + 134479872);     //    524288
  unsigned short*     wxt_l = (unsigned short*)(ws + 135004160);     //    524288
  float*              W2w   = (float*)(ws + 135528448);              //    262144
  float*              bww   = (float*)(ws + 135790592);              //      2048
  unsigned short*     whf_h = (unsigned short*)(ws + 135792640);     //    524288
  unsigned short*     whf_l = (unsigned short*)(ws + 136316928);     //    524288
  unsigned long long* hbuf  = (unsigned long long*)(ws + 136841216); //    557056

  k_wxt <<<256, 256, 0, stream>>>(wx, wxt_h, wxt_l);
  k_whf <<<1024, 256, 0, stream>>>(wh, whf_h, whf_l);
  k_w2  <<<128, 512, 0, stream>>>(at, wm, W2w);
  k_bw  <<<1, 512, 0, stream>>>(bt, wm, bww);
  k_ux  <<<1024, 256, 0, stream>>>(x, ie, uxp);
  k_gemm<<<2048, 256, 0, stream>>>(x, wxt_h, wxt_l, P);
  k_scan<<<256, 512, 0, stream>>>(he, me, bt, at, whf_h, whf_l, W2w, bww,
                                  P, uxp, out, hbuf);
}